// Round 2
// 197.722 us; speedup vs baseline: 1.0767x; 1.0767x over previous
//
#include <hip/hip_runtime.h>
#include <hip/hip_bf16.h>

// PatchAttentionLayer, restructured (R8, resubmit after infra failure):
//   gram: per-block fp32 partial tiles (NO atomics, no memset), partial rowsums.
//         R8: software-pipelined K-loop (register prefetch of next 64-col chunk
//         issued before the MFMA barrier); zeroes Ghat for the atomic reduce.
//   reduce_mirror: R8: b-split grid (385 blocks, was 49). Each block sums the 8
//         ks-partials of one (tt,sub,b) -> Gbf (bf16, mirrored); Ghat built via
//         fp32 atomicAdd (zeroed in gram). fp32 G never materialized.
//   stats: R8: o-grouped (4 outs/block, grid (64,3), was (256,3)) -> 4x less
//         Ghat re-read; shuffle-based dual reduction.
//   zmida: {Z = Wk'^T Wq' (MFMA) | mid_a matvecs} fused.
//   bcF:   {mid_bc (offv, hb; reads Gbf) | F_b = G_b Z (MFMA)} fused.
//   gemm_T: T_b = Wv' F_b + rank-1 epilogue -> bf16 T.
//   out: out_b = T_b x_b + off 1^T (MFMA).
// 7 dispatches total.

#define BB 8
#define CC 256
#define NPIX 4096
#define PTOT 32768
#define EPSV 1e-5f
#define SCALEV 0.125f

// ---- workspace layout (float offsets) ----
#define OFF_PG    0L          // 192*16384 = 3145728 (gram partials)
#define OFF_SP    3145728L    // 16384 (rowsum partials)
#define OFF_S     3162112L    // 2048
#define OFF_GHAT  3164160L    // 65536
#define OFF_XBAR  3229696L    // 256
#define OFF_WP    3229952L    // 196608
#define OFF_WKTF  3426560L    // 65536
#define OFF_WVTF  3492096L    // 65536
#define OFF_CVEC  3557632L    // 768
#define OFF_U     3558400L    // 2048
#define OFF_W2    3560448L    // 2048
#define OFF_HB    3562496L    // 2048
#define OFF_Y     3564544L    // 256
#define OFF_R     3564800L    // 256
#define OFF_OFFV  3565056L    // 2048
#define OFF_GBF   3567104L    // 8*65536 ushort = 262144 floats
#define OFF_WQT   3829248L    // 32768
#define OFF_WKT   3862016L    // 32768
#define OFF_WVB   3894784L    // 32768
#define OFF_ZT    3927552L    // 32768
#define OFF_FT    3960320L    // 262144
#define OFF_TBF   4222464L    // 262144
// total 4484608 floats = 17.9 MB

typedef __attribute__((ext_vector_type(8))) short short8;
typedef __attribute__((ext_vector_type(4))) float f32x4;

#define MFMA16(a, b, c) __builtin_amdgcn_mfma_f32_16x16x32_bf16((a), (b), (c), 0, 0, 0)

__device__ __forceinline__ ushort f2bf(float f) {
    union { float f; unsigned u; } v; v.f = f;
    const unsigned r = (v.u + 0x7FFFu + ((v.u >> 16) & 1u)) >> 16;
    return (ushort)r;
}

__device__ __forceinline__ float bf2f(ushort u) {
    union { unsigned u; float f; } v; v.u = ((unsigned)u) << 16;
    return v.f;
}

// packed RNE f32x2 -> bf16x2 (v_cvt_pk_bf16_f32 on gfx950)
__device__ __forceinline__ ushort2 f2bf2(float a, float b) {
    __hip_bfloat162 h = __float22bfloat162_rn(float2{a, b});
    union { __hip_bfloat162 h; ushort2 u; } v; v.h = h;
    return v.u;
}

__device__ __forceinline__ float block_reduce(float v, float* red, int tid) {
    red[tid] = v; __syncthreads();
    for (int st = 128; st > 0; st >>= 1) {
        if (tid < st) red[tid] += red[tid + st];
        __syncthreads();
    }
    float r = red[0]; __syncthreads();
    return r;
}

// dual wave-shuffle block reduction (sum of a and b over 256 threads)
__device__ __forceinline__ float2 wred2(float a, float b, float* red8, int tid) {
    #pragma unroll
    for (int s = 32; s > 0; s >>= 1) {
        a += __shfl_xor(a, s);
        b += __shfl_xor(b, s);
    }
    if ((tid & 63) == 0) { red8[(tid >> 6) * 2] = a; red8[(tid >> 6) * 2 + 1] = b; }
    __syncthreads();
    const float ra = red8[0] + red8[2] + red8[4] + red8[6];
    const float rb = red8[1] + red8[3] + red8[5] + red8[7];
    __syncthreads();
    return float2{ra, rb};
}

// ---- Gram via MFMA: 128x128 upper tiles, ks=8, partial-tile stores, no atomics ----
// grid (8 ks, 8 b, 3 tt): tt=0 -> (0,0); tt=1 -> (1,1); tt=2 -> (0,1)
// R8: register-prefetch pipeline over kc; also zeroes Ghat (first 64 blocks).
__global__ __launch_bounds__(256) void gram_mfma(const float* __restrict__ x,
                                                 float* __restrict__ Pg,
                                                 float* __restrict__ Sp,
                                                 float* __restrict__ Ghat) {
    __shared__ __align__(16) ushort Ab[128 * 72];
    __shared__ __align__(16) ushort Bb[128 * 72];
    __shared__ float rs[128];
    const int tid = threadIdx.x;
    const int ks = blockIdx.x, b = blockIdx.y, tt = blockIdx.z;
    const int lb = (tt * 8 + b) * 8 + ks;
    if (lb < 64) {
        #pragma unroll
        for (int i = 0; i < 4; ++i) Ghat[lb * 1024 + i * 256 + tid] = 0.f;
    }
    const int it = (tt == 1) ? 1 : 0;
    const int jt = (tt == 0) ? 0 : 1;
    const bool diag = (tt < 2);
    const int i0 = it * 128, j0 = jt * 128, k0 = ks * 512;
    const float* xb = x + (long)b * CC * NPIX;
    const int c = tid & 15, rp = tid >> 4;
    const int wave = tid >> 6, lane = tid & 63;
    const int wr = (wave >> 1) * 64, wc = (wave & 1) * 64;
    const int m = lane & 15, q8 = (lane >> 4) * 8;

    if (tid < 128) rs[tid] = 0.f;
    float rloc[8] = {};
    f32x4 acc[4][4];
    #pragma unroll
    for (int a = 0; a < 4; ++a)
        #pragma unroll
        for (int q = 0; q < 4; ++q) acc[a][q] = (f32x4){0.f, 0.f, 0.f, 0.f};

    const float* Abase = xb + (long)i0 * NPIX + k0 + c * 4;
    const float* Bbase = xb + (long)j0 * NPIX + k0 + c * 4;

    // prefetch kc=0 into registers
    float4 va[8], vb[8];
    #pragma unroll
    for (int pp = 0; pp < 8; ++pp)
        va[pp] = *(const float4*)&Abase[(long)(pp * 16 + rp) * NPIX];
    if (!diag) {
        #pragma unroll
        for (int pp = 0; pp < 8; ++pp)
            vb[pp] = *(const float4*)&Bbase[(long)(pp * 16 + rp) * NPIX];
    }

    for (int kc = 0; kc < 512; kc += 64) {
        __syncthreads();   // previous iteration's MFMA reads done
        #pragma unroll
        for (int pp = 0; pp < 8; ++pp) {
            const int row = pp * 16 + rp;
            const float4 v = va[pp];
            rloc[pp] += v.x + v.y + v.z + v.w;
            const ushort2 w01 = f2bf2(v.x, v.y);
            const ushort2 w23 = f2bf2(v.z, v.w);
            ushort4 w; w.x = w01.x; w.y = w01.y; w.z = w23.x; w.w = w23.y;
            *(ushort4*)&Ab[row * 72 + c * 4] = w;
        }
        if (!diag) {
            #pragma unroll
            for (int pp = 0; pp < 8; ++pp) {
                const int row = pp * 16 + rp;
                const float4 v = vb[pp];
                const ushort2 w01 = f2bf2(v.x, v.y);
                const ushort2 w23 = f2bf2(v.z, v.w);
                ushort4 w; w.x = w01.x; w.y = w01.y; w.z = w23.x; w.w = w23.y;
                *(ushort4*)&Bb[row * 72 + c * 4] = w;
            }
        }
        // issue next chunk's loads NOW: they stay in flight across the MFMA phase
        const int kn = kc + 64;
        if (kn < 512) {
            #pragma unroll
            for (int pp = 0; pp < 8; ++pp)
                va[pp] = *(const float4*)&Abase[(long)(pp * 16 + rp) * NPIX + kn];
            if (!diag) {
                #pragma unroll
                for (int pp = 0; pp < 8; ++pp)
                    vb[pp] = *(const float4*)&Bbase[(long)(pp * 16 + rp) * NPIX + kn];
            }
        }
        __syncthreads();   // LDS writes visible
        const ushort* Bsrc = diag ? Ab : Bb;
        #pragma unroll
        for (int kk = 0; kk < 2; ++kk) {
            short8 af[4], bfv[4];
            #pragma unroll
            for (int a = 0; a < 4; ++a)
                af[a] = *(const short8*)&Ab[(wr + a * 16 + m) * 72 + kk * 32 + q8];
            #pragma unroll
            for (int q = 0; q < 4; ++q)
                bfv[q] = *(const short8*)&Bsrc[(wc + q * 16 + m) * 72 + kk * 32 + q8];
            #pragma unroll
            for (int a = 0; a < 4; ++a)
                #pragma unroll
                for (int q = 0; q < 4; ++q)
                    acc[a][q] = MFMA16(af[a], bfv[q], acc[a][q]);
        }
    }
    if (diag) {
        #pragma unroll
        for (int pp = 0; pp < 8; ++pp) atomicAdd(&rs[pp * 16 + rp], rloc[pp]);
        __syncthreads();
        if (tid < 128) Sp[(((long)ks * 8 + b) * 2 + it) * 128 + tid] = rs[tid];
    }
    float* Pt = Pg + (((long)ks * 8 + b) * 3 + tt) * 16384;
    const int rq = (lane >> 4) * 4;
    #pragma unroll
    for (int a = 0; a < 4; ++a) {
        #pragma unroll
        for (int q = 0; q < 4; ++q) {
            const int col = wc + q * 16 + m;
            #pragma unroll
            for (int reg = 0; reg < 4; ++reg)
                Pt[(long)(wr + a * 16 + rq + reg) * 128 + col] = acc[a][q][reg];
        }
    }
}

// ---- reduce partials -> Gbf (full, mirrored), Ghat (atomic); S; xbar ----
// R8 grid: 385 blocks. blk<384: (tt = blk>>7, sub = (blk>>3)&15, b = blk&7),
// each sums 8 ks-partials of one 32x32 subtile of one batch. blk==384: S/xbar.
__global__ __launch_bounds__(256) void reduce_mirror(const float* __restrict__ Pg,
                                                     const float* __restrict__ Sp,
                                                     ushort* __restrict__ Gbf,
                                                     float* __restrict__ Ghat,
                                                     float* __restrict__ S,
                                                     float* __restrict__ xbar) {
    const int blk = blockIdx.x, tid = threadIdx.x;
    if (blk == 384) {
        const int it2 = tid >> 7, rr = tid & 127;
        float xacc = 0.f;
        for (int b = 0; b < BB; ++b) {
            float acc = 0.f;
            #pragma unroll
            for (int ks = 0; ks < 8; ++ks)
                acc += Sp[(((long)ks * 8 + b) * 2 + it2) * 128 + rr];
            S[b * 256 + tid] = acc;
            xacc += acc;
        }
        xbar[tid] = xacc * (1.0f / PTOT);
        return;
    }
    __shared__ float tile[32][33];
    const int tt = blk >> 7;
    const int sub = (blk >> 3) & 15;
    const int b = blk & 7;
    const int sr = (sub >> 2) * 32, sc = (sub & 3) * 32;
    const int it = (tt == 1) ? 1 : 0;
    const int jt = (tt == 0) ? 0 : 1;
    const bool offd = (tt == 2);
    const int gi0 = it * 128 + sr, gj0 = jt * 128 + sc;
    const int r = tid >> 3, c4 = (tid & 7) * 4;
    const float inv = 1.0f / PTOT;

    float s0 = 0.f, s1 = 0.f, s2 = 0.f, s3 = 0.f;
    #pragma unroll
    for (int ks = 0; ks < 8; ++ks) {
        const float4 v = *(const float4*)&Pg[(((long)ks * 8 + b) * 3 + tt) * 16384
                                             + (long)(sr + r) * 128 + sc + c4];
        s0 += v.x; s1 += v.y; s2 += v.z; s3 += v.w;
    }
    ushort4 w;
    w.x = f2bf(s0); w.y = f2bf(s1); w.z = f2bf(s2); w.w = f2bf(s3);
    *(ushort4*)&Gbf[(long)b * 65536 + (long)(gi0 + r) * 256 + gj0 + c4] = w;
    float* gd = &Ghat[(long)(gi0 + r) * 256 + gj0 + c4];
    atomicAdd(gd + 0, s0 * inv);
    atomicAdd(gd + 1, s1 * inv);
    atomicAdd(gd + 2, s2 * inv);
    atomicAdd(gd + 3, s3 * inv);
    if (offd) {
        tile[r][c4 + 0] = s0; tile[r][c4 + 1] = s1;
        tile[r][c4 + 2] = s2; tile[r][c4 + 3] = s3;
        __syncthreads();
        const float t0 = tile[c4 + 0][r], t1 = tile[c4 + 1][r];
        const float t2 = tile[c4 + 2][r], t3 = tile[c4 + 3][r];
        ushort4 tw;
        tw.x = f2bf(t0); tw.y = f2bf(t1); tw.z = f2bf(t2); tw.w = f2bf(t3);
        *(ushort4*)&Gbf[(long)b * 65536 + (long)(gj0 + r) * 256 + gi0 + c4] = tw;
        float* gm = &Ghat[(long)(gj0 + r) * 256 + gi0 + c4];
        atomicAdd(gm + 0, t0 * inv);
        atomicAdd(gm + 1, t1 * inv);
        atomicAdd(gm + 2, t2 * inv);
        atomicAdd(gm + 3, t3 * inv);
    }
}

// ---- BN stats; writes fp32 Wp (+ fp32 transposes of Wk',Wv'), bf16 mats, cvec ----
// R8: grid (64 ogroups, 3 t); 4 output channels per block (4x Ghat reuse).
__global__ __launch_bounds__(256) void stats_quad(const float* __restrict__ Wq, const float* __restrict__ Wk,
                           const float* __restrict__ Wv, const float* __restrict__ Ghat,
                           const float* __restrict__ xbar,
                           const float* bq, const float* gq, const float* betaq,
                           const float* bk, const float* gk, const float* betak,
                           const float* bv, const float* gv, const float* betav,
                           float* __restrict__ Wp, float* __restrict__ cvec,
                           ushort* __restrict__ WqT, ushort* __restrict__ WkT,
                           ushort* __restrict__ Wvb, float* __restrict__ WkTf,
                           float* __restrict__ WvTf) {
    const int og = blockIdx.x, t = blockIdx.y, tid = threadIdx.x;
    const int o0 = og * 4;
    const float* Wt  = t == 0 ? Wq : (t == 1 ? Wk : Wv);
    const float* bt  = t == 0 ? bq : (t == 1 ? bk : bv);
    const float* gt  = t == 0 ? gq : (t == 1 ? gk : gv);
    const float* bet = t == 0 ? betaq : (t == 1 ? betak : betav);
    __shared__ float wrows[4][256];
    __shared__ float red8[8];
    #pragma unroll
    for (int i = 0; i < 4; ++i) wrows[i][tid] = Wt[(o0 + i) * 256 + tid];
    const float xb = xbar[tid];
    __syncthreads();
    const float* grow = Ghat + (long)tid * 256;
    float tj[4] = {0.f, 0.f, 0.f, 0.f};
    #pragma unroll 8
    for (int k = 0; k < 256; k += 4) {
        const float4 g = *(const float4*)&grow[k];
        #pragma unroll
        for (int i = 0; i < 4; ++i)
            tj[i] += g.x * wrows[i][k]     + g.y * wrows[i][k + 1]
                   + g.z * wrows[i][k + 2] + g.w * wrows[i][k + 3];
    }
    #pragma unroll
    for (int i = 0; i < 4; ++i) {
        const int o = o0 + i;
        const float wv = wrows[i][tid];
        const float2 qw = wred2(wv * tj[i], wv * xb, red8, tid);
        const float bo = bt[o];
        const float mu = qw.y + bo;
        const float var = qw.x + 2.f * bo * mu - bo * bo - mu * mu;
        const float a = gt[o] * rsqrtf(var + EPSV);
        const float wpv = a * wv;
        Wp[(long)t * 65536 + o * 256 + tid] = wpv;
        const ushort wb = f2bf(wpv);
        if (t == 0) {
            WqT[(long)tid * 256 + o] = wb;
        } else if (t == 1) {
            WkT[(long)tid * 256 + o] = wb;
            WkTf[(long)tid * 256 + o] = wpv;
        } else {
            Wvb[(long)o * 256 + tid] = wb;
            WvTf[(long)tid * 256 + o] = wpv;
        }
        if (tid == 0) cvec[t * 256 + o] = a * (bo - mu) + bet[o];
    }
}

// ---- shared MFMA 128x128-tile GEMM body, K=256, fragments direct from L2 ----
__device__ __forceinline__ void gemm_tile(const ushort* __restrict__ Ab,
                                          const ushort* __restrict__ Bb,
                                          ushort* __restrict__ Db,
                                          int m0, int n0, int mode, int bz,
                                          const float* __restrict__ u,
                                          const float* __restrict__ cvec,
                                          const float* __restrict__ r,
                                          const float* __restrict__ hb, int tid) {
    const int wave = tid >> 6, lane = tid & 63;
    const int wr = (wave >> 1) * 64, wc = (wave & 1) * 64;
    const int m = lane & 15, q8 = (lane >> 4) * 8;
    f32x4 acc[4][4];
    #pragma unroll
    for (int a = 0; a < 4; ++a)
        #pragma unroll
        for (int q = 0; q < 4; ++q) acc[a][q] = (f32x4){0.f, 0.f, 0.f, 0.f};
    #pragma unroll
    for (int kk = 0; kk < 8; ++kk) {
        short8 af[4], bfv[4];
        #pragma unroll
        for (int a = 0; a < 4; ++a)
            af[a] = *(const short8*)&Ab[(long)(m0 + wr + a * 16 + m) * 256 + kk * 32 + q8];
        #pragma unroll
        for (int q = 0; q < 4; ++q)
            bfv[q] = *(const short8*)&Bb[(long)(n0 + wc + q * 16 + m) * 256 + kk * 32 + q8];
        #pragma unroll
        for (int a = 0; a < 4; ++a)
            #pragma unroll
            for (int q = 0; q < 4; ++q)
                acc[a][q] = MFMA16(af[a], bfv[q], acc[a][q]);
    }
    const int rq = (lane >> 4) * 4;
    #pragma unroll
    for (int a = 0; a < 4; ++a) {
        #pragma unroll
        for (int q = 0; q < 4; ++q) {
            const int col = n0 + wc + q * 16 + m;
            #pragma unroll
            for (int reg = 0; reg < 4; ++reg) {
                const int row = m0 + wr + a * 16 + rq + reg;
                const float v = acc[a][q][reg];
                if (mode == 0) {
                    Db[(long)col * 256 + row] = f2bf(v);
                } else {
                    const float rv = r[col];
                    const float t2 = hb[bz * 256 + col] + 4096.0f * rv;
                    const float val = SCALEV * (v + u[bz * 256 + row] * rv + cvec[512 + row] * t2);
                    Db[(long)row * 256 + col] = f2bf(val);
                }
            }
        }
    }
}

// ---- fused: blocks 0-3 = Z GEMM tiles; blocks 4-12 = mid_a ----
__global__ __launch_bounds__(256) void zmida(const ushort* __restrict__ WkT,
                                             const ushort* __restrict__ WqT,
                                             ushort* __restrict__ ZT,
                                             const float* __restrict__ Wp,
                                             const float* __restrict__ WkTf,
                                             const float* __restrict__ WvTf,
                                             const float* __restrict__ S,
                                             const float* __restrict__ cvec,
                                             float* __restrict__ u, float* __restrict__ w,
                                             float* __restrict__ y, float* __restrict__ r) {
    const int blk = blockIdx.x, tid = threadIdx.x;
    if (blk < 4) {
        gemm_tile(WkT, WqT, ZT, (blk >> 1) * 128, (blk & 1) * 128, 0, 0,
                  nullptr, nullptr, nullptr, nullptr, tid);
        return;
    }
    const int bidx = blk - 4;
    if (bidx < 8) {
        __shared__ float sh[256];
        sh[tid] = S[bidx * 256 + tid]; __syncthreads();
        float uu = 0.f, ww = 0.f;
        #pragma unroll 8
        for (int j = 0; j < 256; ++j) {
            uu += WvTf[(long)j * 256 + tid] * sh[j];
            ww += WkTf[(long)j * 256 + tid] * sh[j];
        }
        u[bidx * 256 + tid] = uu;
        w[bidx * 256 + tid] = ww;
    } else {
        __shared__ float cqs[256], cks[256];
        cqs[tid] = cvec[tid]; cks[tid] = cvec[256 + tid]; __syncthreads();
        float yy = 0.f, rr = 0.f;
        #pragma unroll 8
        for (int o = 0; o < 256; ++o) {
            yy += Wp[65536L + (long)o * 256 + tid] * cqs[o];
            rr += Wp[(long)o * 256 + tid] * cks[o];
        }
        y[tid] = yy;
        r[tid] = rr;
    }
}

// ---- fused: blocks 0-7 = mid_bc (reads Gbf); blocks 8-39 = F GEMM tiles ----
__global__ __launch_bounds__(256) void bcF(const float* __restrict__ Wp,
                                           const ushort* __restrict__ Gbf,
                                           const float* __restrict__ WvTf,
                                           const float* __restrict__ w,
                                           const float* __restrict__ y,
                                           const float* __restrict__ u,
                                           const float* __restrict__ cvec,
                                           float* __restrict__ hb,
                                           float* __restrict__ offv,
                                           const ushort* __restrict__ ZT,
                                           ushort* __restrict__ FT) {
    const int blk = blockIdx.x, tid = threadIdx.x;
    if (blk >= 8) {
        const int idx = blk - 8;
        const int bz = idx >> 2, t = idx & 3;
        gemm_tile(Gbf + (long)bz * 65536, ZT, FT + (long)bz * 65536,
                  (t >> 1) * 128, (t & 1) * 128, 0, 0,
                  nullptr, nullptr, nullptr, nullptr, tid);
        return;
    }
    const int b = blk;
    __shared__ float wl[256], yl[256], gyl[256], red[256], cqs[256], cks[256];
    wl[tid] = w[b * 256 + tid];
    yl[tid] = y[tid];
    cqs[tid] = cvec[tid];
    cks[tid] = cvec[256 + tid];
    const float cv = cvec[512 + tid];
    const float uu = u[b * 256 + tid];
    __syncthreads();
    float hh = 0.f, gg = 0.f;
    #pragma unroll 8
    for (int o = 0; o < 256; ++o) {
        hh += Wp[(long)o * 256 + tid] * wl[o];
        gg += bf2f(Gbf[(long)b * 65536 + (long)o * 256 + tid]) * yl[o];
    }
    hb[b * 256 + tid] = hh;
    gyl[tid] = gg;
    __syncthreads();
    float vg = 0.f;
    #pragma unroll 8
    for (int j = 0; j < 256; ++j) vg += WvTf[(long)j * 256 + tid] * gyl[j];
    const float dkq = block_reduce(cqs[tid] * cks[tid], red, tid);
    const float dwq = block_reduce(wl[tid] * cqs[tid], red, tid);
    offv[b * 256 + tid] = SCALEV * (vg + uu * dkq + cv * (dwq + 4096.0f * dkq));
}

// ---- T_b = Wv' F_b + rank-1, scaled -> Tbf. grid (2,2,8) ----
__global__ __launch_bounds__(256) void gemm_T(const ushort* __restrict__ Wvb,
                                              const ushort* __restrict__ FT,
                                              ushort* __restrict__ Tbf,
                                              const float* __restrict__ u,
                                              const float* __restrict__ cvec,
                                              const float* __restrict__ r,
                                              const float* __restrict__ hb) {
    const int bz = blockIdx.z;
    gemm_tile(Wvb, FT + (long)bz * 65536, Tbf + (long)bz * 65536,
              blockIdx.y * 128, blockIdx.x * 128, 1, bz, u, cvec, r, hb, threadIdx.x);
}

// ---- out_b = T_b x_b + off_b via MFMA; 64-pixel tiles; grid (64, 8) ----
__global__ __launch_bounds__(256) void out_mfma(const ushort* __restrict__ Tbf,
                                                const float* __restrict__ x,
                                                const float* __restrict__ offv,
                                                float* __restrict__ out) {
    __shared__ __align__(16) ushort Bs[64 * 264];
    const int tid = threadIdx.x;
    const int p0 = blockIdx.x * 64;
    const int b = blockIdx.y;
    const float* xb = x + (long)b * CC * NPIX;
    const ushort* Tb = Tbf + (long)b * 65536;

    const int c = tid & 15, kq = tid >> 4;
    #pragma unroll
    for (int kt = 0; kt < 4; ++kt) {
        const int k4 = kt * 64 + kq * 4;
        const int p = c * 4;
        const float4 v0 = *(const float4*)&xb[(long)(k4 + 0) * NPIX + p0 + p];
        const float4 v1 = *(const float4*)&xb[(long)(k4 + 1) * NPIX + p0 + p];
        const float4 v2 = *(const float4*)&xb[(long)(k4 + 2) * NPIX + p0 + p];
        const float4 v3 = *(const float4*)&xb[(long)(k4 + 3) * NPIX + p0 + p];
        ushort2 a01, a23;
        ushort4 w;
        a01 = f2bf2(v0.x, v1.x); a23 = f2bf2(v2.x, v3.x);
        w.x = a01.x; w.y = a01.y; w.z = a23.x; w.w = a23.y;
        *(ushort4*)&Bs[(p + 0) * 264 + k4] = w;
        a01 = f2bf2(v0.y, v1.y); a23 = f2bf2(v2.y, v3.y);
        w.x = a01.x; w.y = a01.y; w.z = a23.x; w.w = a23.y;
        *(ushort4*)&Bs[(p + 1) * 264 + k4] = w;
        a01 = f2bf2(v0.z, v1.z); a23 = f2bf2(v2.z, v3.z);
        w.x = a01.x; w.y = a01.y; w.z = a23.x; w.w = a23.y;
        *(ushort4*)&Bs[(p + 2) * 264 + k4] = w;
        a01 = f2bf2(v0.w, v1.w); a23 = f2bf2(v2.w, v3.w);
        w.x = a01.x; w.y = a01.y; w.z = a23.x; w.w = a23.y;
        *(ushort4*)&Bs[(p + 3) * 264 + k4] = w;
    }
    __syncthreads();

    const int wave = tid >> 6, lane = tid & 63;
    const int wr = wave * 64;
    const int m = lane & 15, q8 = (lane >> 4) * 8;
    f32x4 acc[4][4];
    #pragma unroll
    for (int a = 0; a < 4; ++a)
        #pragma unroll
        for (int q = 0; q < 4; ++q) acc[a][q] = (f32x4){0.f, 0.f, 0.f, 0.f};

    #pragma unroll
    for (int kk = 0; kk < 8; ++kk) {
        short8 af[4], bfv[4];
        #pragma unroll
        for (int a = 0; a < 4; ++a)
            af[a] = *(const short8*)&Tb[(long)(wr + a * 16 + m) * 256 + kk * 32 + q8];
        #pragma unroll
        for (int q = 0; q < 4; ++q)
            bfv[q] = *(const short8*)&Bs[(q * 16 + m) * 264 + kk * 32 + q8];
        #pragma unroll
        for (int a = 0; a < 4; ++a)
            #pragma unroll
            for (int q = 0; q < 4; ++q)
                acc[a][q] = MFMA16(af[a], bfv[q], acc[a][q]);
    }

    const int rq = (lane >> 4) * 4;
    #pragma unroll
    for (int a = 0; a < 4; ++a) {
        #pragma unroll
        for (int reg = 0; reg < 4; ++reg) {
            const int row = wr + a * 16 + rq + reg;
            const float off_ = offv[b * CC + row];
            float* orow = &out[((long)b * CC + row) * NPIX + p0];
            #pragma unroll
            for (int q = 0; q < 4; ++q)
                orow[q * 16 + m] = acc[a][q][reg] + off_;
        }
    }
}

extern "C" void kernel_launch(void* const* d_in, const int* in_sizes, int n_in,
                              void* d_out, int out_size, void* d_ws, size_t ws_size,
                              hipStream_t stream) {
    const float* x     = (const float*)d_in[0];
    const float* Wq    = (const float*)d_in[1];
    const float* bq    = (const float*)d_in[2];
    const float* gq    = (const float*)d_in[3];
    const float* betaq = (const float*)d_in[4];
    const float* Wk    = (const float*)d_in[5];
    const float* bk    = (const float*)d_in[6];
    const float* gk    = (const float*)d_in[7];
    const float* betak = (const float*)d_in[8];
    const float* Wv    = (const float*)d_in[9];
    const float* bv    = (const float*)d_in[10];
    const float* gv    = (const float*)d_in[11];
    const float* betav = (const float*)d_in[12];
    float* ws = (float*)d_ws;

    float*  Pg   = ws + OFF_PG;
    float*  Sp   = ws + OFF_SP;
    float*  S    = ws + OFF_S;
    float*  Ghat = ws + OFF_GHAT;
    float*  Xbar = ws + OFF_XBAR;
    float*  Wp   = ws + OFF_WP;
    float*  WkTf = ws + OFF_WKTF;
    float*  WvTf = ws + OFF_WVTF;
    float*  cvec = ws + OFF_CVEC;
    float*  U    = ws + OFF_U;
    float*  W2   = ws + OFF_W2;
    float*  Hb   = ws + OFF_HB;
    float*  Y    = ws + OFF_Y;
    float*  R    = ws + OFF_R;
    float*  OffV = ws + OFF_OFFV;
    ushort* Gbf  = (ushort*)(ws + OFF_GBF);
    ushort* WqT  = (ushort*)(ws + OFF_WQT);
    ushort* WkT  = (ushort*)(ws + OFF_WKT);
    ushort* Wvb  = (ushort*)(ws + OFF_WVB);
    ushort* ZT   = (ushort*)(ws + OFF_ZT);
    ushort* FT   = (ushort*)(ws + OFF_FT);
    ushort* Tbf  = (ushort*)(ws + OFF_TBF);

    gram_mfma<<<dim3(8, 8, 3), 256, 0, stream>>>(x, Pg, Sp, Ghat);
    reduce_mirror<<<385, 256, 0, stream>>>(Pg, Sp, Gbf, Ghat, S, Xbar);
    stats_quad<<<dim3(64, 3), 256, 0, stream>>>(Wq, Wk, Wv, Ghat, Xbar,
                                                bq, gq, betaq, bk, gk, betak,
                                                bv, gv, betav, Wp, cvec,
                                                WqT, WkT, Wvb, WkTf, WvTf);
    zmida<<<13, 256, 0, stream>>>(WkT, WqT, ZT, Wp, WkTf, WvTf, S, cvec, U, W2, Y, R);
    bcF<<<40, 256, 0, stream>>>(Wp, Gbf, WvTf, W2, Y, U, cvec, Hb, OffV, ZT, FT);
    gemm_T<<<dim3(2, 2, 8), 256, 0, stream>>>(Wvb, FT, Tbf, U, cvec, R, Hb);
    out_mfma<<<dim3(64, 8), 256, 0, stream>>>(Tbf, x, OffV, (float*)d_out);
}